// Round 4
// baseline (5228.805 us; speedup 1.0000x reference)
//
#include <hip/hip_runtime.h>
#include <hip/hip_fp16.h>

#define C_    15
#define H_    256
#define O_    512
#define T_    60
#define B_    1024
#define G3H_  768
#define TS    16
#define MAXG  12
#define NSLOT 96
#define NCOL  1280        // 768 gh + 512 out cols per camera
#define KB    16          // blocks per camera
#define NTB   5           // ntiles per block (80 cols)
#define MAXR  1040        // padded rows per camera buffer

typedef __attribute__((ext_vector_type(8))) short bf16x8;
typedef __attribute__((ext_vector_type(4))) float f32x4;

__device__ __forceinline__ unsigned short f2bf(float f) {
    union { float f; unsigned u; } v; v.f = f;
    return (unsigned short)((v.u + 0x7FFFu + ((v.u >> 16) & 1u)) >> 16);   // RTNE
}
__device__ __forceinline__ float sigf(float x) { return 1.f / (1.f + __expf(-x)); }

// ---------------- sort: camera grouping + gi tile tables + per-camera start/cnt ----------------
__global__ __launch_bounds__(256) void sort_kernel(const int* __restrict__ cam,
    int* __restrict__ order, int* __restrict__ tcam, int* __restrict__ toff,
    int* __restrict__ tcnt, int* __restrict__ cstart, int* __restrict__ ccnt)
{
    __shared__ int cnt[C_], start[C_], fill[C_];
    int tid = threadIdx.x;
    if (tid < C_) cnt[tid] = 0;
    if (tid < NSLOT) { tcam[tid] = -1; toff[tid] = 0; tcnt[tid] = 0; }
    __syncthreads();
    for (int b = tid; b < B_; b += 256) atomicAdd(&cnt[cam[b]], 1);
    __syncthreads();
    if (tid == 0) {
        int run = 0;
        for (int c = 0; c < C_; ++c) { start[c] = run; fill[c] = run; run += cnt[c]; }
    }
    __syncthreads();
    if (tid < C_) { cstart[tid] = start[tid]; ccnt[tid] = cnt[tid]; }
    for (int b = tid; b < B_; b += 256) {
        int pos = atomicAdd(&fill[cam[b]], 1);
        order[pos] = b;
    }
    __syncthreads();
    if (tid == 0) {
        int gcnt[8] = {0,0,0,0,0,0,0,0};
        for (int c = 0; c < C_; ++c) gcnt[c & 7] += (cnt[c] + TS - 1) / TS;
        int maxg = 0;
        for (int g = 0; g < 8; ++g) maxg = max(maxg, gcnt[g]);
        if (maxg <= MAXG) {
            for (int g = 0; g < 8; ++g) {
                int k = 0;
                for (int c = g; c < C_; c += 8)
                    for (int r = 0; r < cnt[c]; r += TS) {
                        int slot = g + 8 * k;
                        tcam[slot] = c; toff[slot] = start[c] + r;
                        tcnt[slot] = min(TS, cnt[c] - r); ++k;
                    }
            }
        } else {
            int ti = 0;
            for (int c = 0; c < C_; ++c)
                for (int r = 0; r < cnt[c]; r += TS) {
                    tcam[ti] = c; toff[ti] = start[c] + r;
                    tcnt[ti] = min(TS, cnt[c] - r); ++ti;
                }
        }
    }
}

// ---------------- fp32 -> bf16 (for Wih only) ----------------
__global__ __launch_bounds__(256) void cvt_kernel(const float* __restrict__ src,
    unsigned short* __restrict__ dst, int n4)
{
    int i = blockIdx.x * 256 + threadIdx.x;
    if (i < n4) {
        float4 v = ((const float4*)src)[i];
        unsigned p0 = (unsigned)f2bf(v.x) | ((unsigned)f2bf(v.y) << 16);
        unsigned p1 = (unsigned)f2bf(v.z) | ((unsigned)f2bf(v.w) << 16);
        ((uint2*)dst)[i] = make_uint2(p0, p1);
    }
}

// ---------------- gi = x*Wih^T + b_ih + b_hh(r,z) via MFMA (from R3, proven) ----------------
__global__ __launch_bounds__(384) void gi_mfma(
    const float* __restrict__ x, const unsigned short* __restrict__ Wih_b,
    const float* __restrict__ bih, const float* __restrict__ bhh,
    const int* __restrict__ order, const int* __restrict__ tcam,
    const int* __restrict__ toff, const int* __restrict__ tcnt,
    float* __restrict__ gi)
{
    int c = tcam[blockIdx.x]; if (c < 0) return;
    int cnt = tcnt[blockIdx.x], off = toff[blockIdx.x];
    int tid = threadIdx.x;
    __shared__ unsigned short hbfs[TS * 264];
    __shared__ int ord16[TS];
    if (tid < TS) ord16[tid] = (tid < cnt) ? order[off + tid] : 0;
    for (int idx = tid; idx < TS * 64; idx += 384) {
        int m = idx >> 6, c4 = idx & 63;
        float4 v = make_float4(0.f, 0.f, 0.f, 0.f);
        if (m < cnt) v = *(const float4*)&x[(size_t)order[off + m] * H_ + (c4 << 2)];
        unsigned p0 = (unsigned)f2bf(v.x) | ((unsigned)f2bf(v.y) << 16);
        unsigned p1 = (unsigned)f2bf(v.z) | ((unsigned)f2bf(v.w) << 16);
        *(uint2*)&hbfs[m * 264 + (c4 << 2)] = make_uint2(p0, p1);
    }
    __syncthreads();
    int w = tid >> 6, lane = tid & 63, q = lane >> 4, l16 = lane & 15;
    f32x4 zero = {0.f, 0.f, 0.f, 0.f};
    f32x4 acc[2][4];
#pragma unroll
    for (int i = 0; i < 2; ++i)
#pragma unroll
        for (int nt = 0; nt < 4; ++nt) acc[i][nt] = zero;
    const unsigned short* bp[2];
#pragma unroll
    for (int i = 0; i < 2; ++i)
        bp[i] = Wih_b + ((size_t)c * G3H_ + (2 * w + i) * 64 + l16) * H_;
    const unsigned short* ap = &hbfs[l16 * 264 + q * 8];
#pragma unroll 2
    for (int kk = 0; kk < 8; ++kk) {
        bf16x8 a = *(const bf16x8*)(ap + kk * 32);
#pragma unroll
        for (int i = 0; i < 2; ++i)
#pragma unroll
            for (int nt = 0; nt < 4; ++nt) {
                bf16x8 b = *(const bf16x8*)(bp[i] + (size_t)nt * 16 * H_ + kk * 32 + q * 8);
                acc[i][nt] = __builtin_amdgcn_mfma_f32_16x16x32_bf16(a, b, acc[i][nt], 0, 0, 0);
            }
    }
#pragma unroll
    for (int i = 0; i < 2; ++i) {
        int u = 2 * w + i;
#pragma unroll
        for (int nt = 0; nt < 4; ++nt) {
            int col = u * 64 + nt * 16 + l16;
            float bias = bih[c * G3H_ + col] + (col < 2 * H_ ? bhh[c * G3H_ + col] : 0.f);
#pragma unroll
            for (int r = 0; r < 4; ++r) {
                int m = q * 4 + r;
                if (m < cnt) gi[(size_t)ord16[m] * G3H_ + col] = acc[i][nt][r] + bias;
            }
        }
    }
}

// ---------------- persistent: all 60 steps, weights in VGPRs ----------------
__global__ __launch_bounds__(256, 1) void persist_kernel(
    const float* __restrict__ Whh, const float* __restrict__ Wc,
    const float* __restrict__ bhh, const float* __restrict__ bc,
    const float* __restrict__ gi, const int* __restrict__ order,
    const int* __restrict__ cstart, const int* __restrict__ ccnt,
    float* __restrict__ hglob, unsigned short* __restrict__ hbf,
    float* __restrict__ Pgh, int* __restrict__ bar,
    unsigned short* __restrict__ outT, int direct, float* __restrict__ outp)
{
    int g = blockIdx.x & 7, k = blockIdx.x >> 3;     // slot%8 -> XCD pin heuristic
    int c = g + 8 * (k >> 4);
    if (c >= C_) return;
    int j = k & 15;                                  // sub-block 0..15 within camera
    int n = ccnt[c]; if (n == 0) return;
    int off = cstart[c];
    int tiles = (n + 15) >> 4;
    int tid = threadIdx.x, w = tid >> 6, lane = tid & 63, q = lane >> 4, l16 = lane & 15;

    float* hc = hglob + (size_t)c * MAXR * H_;
    unsigned short* hbc = hbf + (size_t)c * MAXR * H_;
    float* Pc = Pgh + (size_t)c * MAXR * G3H_;
    int* cnt_p = bar + c * 32;

    // ---- load B fragments once: 5 nt x 8 kk x 4 VGPRs = 160 VGPRs of weights ----
    bf16x8 bfr[NTB][8];
#pragma unroll
    for (int nt = 0; nt < NTB; ++nt) {
        int col = j * 80 + nt * 16 + l16;
        const float* src = (col < G3H_)
            ? &Whh[((size_t)c * G3H_ + col) * H_]
            : &Wc[((size_t)c * O_ + (col - G3H_)) * H_];
#pragma unroll
        for (int kk = 0; kk < 8; ++kk) {
            float4 v0 = *(const float4*)&src[kk * 32 + q * 8];
            float4 v1 = *(const float4*)&src[kk * 32 + q * 8 + 4];
            bf16x8 t;
            t[0] = (short)f2bf(v0.x); t[1] = (short)f2bf(v0.y);
            t[2] = (short)f2bf(v0.z); t[3] = (short)f2bf(v0.w);
            t[4] = (short)f2bf(v1.x); t[5] = (short)f2bf(v1.y);
            t[6] = (short)f2bf(v1.z); t[7] = (short)f2bf(v1.w);
            bfr[nt][kk] = t;
        }
    }
    float bhn = bhh[c * G3H_ + 2 * H_ + tid];        // n-gate bias for update col tid
    int epoch = 0;

    for (int s = 0; s <= T_; ++s) {
        // ---- phase A: preacts from h_s (hbc); out for t = s-1 ----
        for (int mt = w; mt < tiles; mt += 4) {
            int m0 = mt * 16;
            f32x4 acc[NTB];
#pragma unroll
            for (int nt = 0; nt < NTB; ++nt) acc[nt] = (f32x4){0.f, 0.f, 0.f, 0.f};
            const unsigned short* ap = &hbc[(size_t)(m0 + l16) * H_];
#pragma unroll
            for (int kk = 0; kk < 8; ++kk) {
                bf16x8 a = *(const bf16x8*)(ap + kk * 32 + q * 8);
#pragma unroll
                for (int nt = 0; nt < NTB; ++nt)
                    acc[nt] = __builtin_amdgcn_mfma_f32_16x16x32_bf16(a, bfr[nt][kk], acc[nt], 0, 0, 0);
            }
#pragma unroll
            for (int nt = 0; nt < NTB; ++nt) {
                int colb = j * 80 + nt * 16;
                if (colb < G3H_) {
                    if (s < T_) {
                        int colx = colb + l16;
#pragma unroll
                        for (int r = 0; r < 4; ++r) {
                            int m = m0 + q * 4 + r;
                            if (m < n) Pc[(size_t)m * G3H_ + colx] = acc[nt][r];
                        }
                    }
                } else if (s > 0) {
                    int o = colb - G3H_ + l16;
                    float bcv = bc[c * O_ + o];
#pragma unroll
                    for (int r = 0; r < 4; ++r) {
                        int m = m0 + q * 4 + r;
                        if (m < n) {
                            int b = order[off + m];
                            float val = sigf(acc[nt][r] + bcv);
                            if (direct) outp[((size_t)b * O_ + o) * T_ + (s - 1)] = val;
                            else outT[((size_t)(s - 1) * B_ + b) * O_ + o] =
                                     __half_as_ushort(__float2half_rn(val));
                        }
                    }
                }
            }
        }
        if (s == T_) break;

        // ---- barrier 1 (camera-local) ----
        __syncthreads();
        __threadfence();
        if (tid == 0) atomicAdd(cnt_p, 1);
        ++epoch;
        if (tid == 0) {
            while (__hip_atomic_load(cnt_p, __ATOMIC_RELAXED, __HIP_MEMORY_SCOPE_AGENT) < KB * epoch)
                __builtin_amdgcn_s_sleep(2);
        }
        __syncthreads();
        __threadfence();

        // ---- phase B: gate update for samples m ≡ j (mod 16), col = tid ----
        for (int m = j; m < n; m += KB) {
            int b = order[off + m];
            float pr = Pc[(size_t)m * G3H_ + tid];
            float pz = Pc[(size_t)m * G3H_ + H_ + tid];
            float pn = Pc[(size_t)m * G3H_ + 2 * H_ + tid];
            const float* gb = gi + (size_t)b * G3H_;
            float rr = sigf(gb[tid] + pr);
            float zz = sigf(gb[H_ + tid] + pz);
            float pre = gb[2 * H_ + tid] + rr * (pn + bhn);
            float nn = 2.f * sigf(2.f * pre) - 1.f;          // tanh
            float hold = hc[(size_t)m * H_ + tid];
            float hnew = (1.f - zz) * nn + zz * hold;
            hc[(size_t)m * H_ + tid] = hnew;
            hbc[(size_t)m * H_ + tid] = f2bf(hnew);
        }

        // ---- barrier 2 ----
        __syncthreads();
        __threadfence();
        if (tid == 0) atomicAdd(cnt_p, 1);
        ++epoch;
        if (tid == 0) {
            while (__hip_atomic_load(cnt_p, __ATOMIC_RELAXED, __HIP_MEMORY_SCOPE_AGENT) < KB * epoch)
                __builtin_amdgcn_s_sleep(2);
        }
        __syncthreads();
        __threadfence();
    }
}

// ---------------- transpose [T][B][O] fp16 -> [B][O][T] fp32 ----------------
__global__ __launch_bounds__(256) void transpose_kernel(
    const unsigned short* __restrict__ outT, float* __restrict__ outp)
{
    int b = blockIdx.x, o0 = blockIdx.y * 64;
    __shared__ float ts[T_][65];
    int tid = threadIdx.x;
    for (int idx = tid; idx < T_ * 64; idx += 256) {
        int t = idx >> 6, o = idx & 63;
        ts[t][o] = __half2float(__ushort_as_half(outT[((size_t)t * B_ + b) * O_ + o0 + o]));
    }
    __syncthreads();
    for (int idx = tid; idx < 64 * T_; idx += 256) {
        int o = idx / T_, t = idx - o * T_;
        outp[((size_t)b * O_ + o0 + o) * T_ + t] = ts[t][o];
    }
}

extern "C" void kernel_launch(void* const* d_in, const int* in_sizes, int n_in,
                              void* d_out, int out_size, void* d_ws, size_t ws_size,
                              hipStream_t stream)
{
    const float* x   = (const float*)d_in[0];
    const int*   cam = (const int*)d_in[1];
    const float* Wih = (const float*)d_in[2];
    const float* Whh = (const float*)d_in[3];
    const float* bih = (const float*)d_in[4];
    const float* bhh = (const float*)d_in[5];
    const float* Wc  = (const float*)d_in[6];
    const float* bc  = (const float*)d_in[7];
    float* outp = (float*)d_out;

    char* w = (char*)d_ws;
    unsigned short* Wih_b = (unsigned short*)w; w += (size_t)C_ * G3H_ * H_ * 2;
    int* order  = (int*)w; w += B_ * 4;
    int* tcam   = (int*)w; w += NSLOT * 4;
    int* toff   = (int*)w; w += NSLOT * 4;
    int* tcnt   = (int*)w; w += NSLOT * 4;
    int* cstart = (int*)w; w += 16 * 4;
    int* ccnt   = (int*)w; w += 16 * 4;
    float* gi   = (float*)w; w += (size_t)B_ * G3H_ * 4;
    float* Pgh  = (float*)w; w += (size_t)C_ * MAXR * G3H_ * 4;
    // zero-region: h, hbf, bar (one memset)
    char* zbase = w;
    float* hglob = (float*)w;          w += (size_t)C_ * MAXR * H_ * 4;
    unsigned short* hbf = (unsigned short*)w; w += (size_t)C_ * MAXR * H_ * 2;
    int* bar    = (int*)w;             w += C_ * 32 * 4;
    size_t zbytes = (size_t)(w - zbase);
    unsigned short* outT = (unsigned short*)w;
    size_t need = (size_t)(w - (char*)d_ws) + (size_t)T_ * B_ * O_ * 2;
    int direct = (ws_size < need) ? 1 : 0;

    sort_kernel<<<1, 256, 0, stream>>>(cam, order, tcam, toff, tcnt, cstart, ccnt);
    cvt_kernel<<<(C_ * G3H_ * H_ / 4 + 255) / 256, 256, 0, stream>>>(Wih, Wih_b, C_ * G3H_ * H_ / 4);
    hipMemsetAsync(zbase, 0, zbytes, stream);
    gi_mfma<<<NSLOT, 384, 0, stream>>>(x, Wih_b, bih, bhh, order, tcam, toff, tcnt, gi);
    persist_kernel<<<256, 256, 0, stream>>>(Whh, Wc, bhh, bc, gi, order, cstart, ccnt,
                                            hglob, hbf, Pgh, bar, outT, direct, outp);
    if (!direct)
        transpose_kernel<<<dim3(B_, O_ / 64), 256, 0, stream>>>(outT, outp);
}

// Round 5
// 1046.797 us; speedup vs baseline: 4.9951x; 4.9951x over previous
//
#include <hip/hip_runtime.h>
#include <hip/hip_fp16.h>

#define C_    15
#define H_    256
#define O_    512
#define T_    60
#define B_    1024
#define G3H_  768
#define TS    16
#define MAXG  12
#define NSLOT 96
#define NU    80          // 16-col units per camera: 48 gh + 32 out
#define UW    10          // units per wave (8 waves)

typedef __attribute__((ext_vector_type(8))) short bf16x8;
typedef __attribute__((ext_vector_type(4))) float f32x4;

__device__ __forceinline__ unsigned short f2bf(float f) {
    union { float f; unsigned u; } v; v.f = f;
    return (unsigned short)((v.u + 0x7FFFu + ((v.u >> 16) & 1u)) >> 16);   // RTNE
}
__device__ __forceinline__ float sigf(float x) { return 1.f / (1.f + __expf(-x)); }

// ---------------- sort: camera grouping, XCD-pinned 16-row tile table ----------------
__global__ __launch_bounds__(256) void sort_kernel(const int* __restrict__ cam,
    int* __restrict__ order, int* __restrict__ tcam, int* __restrict__ toff,
    int* __restrict__ tcnt)
{
    __shared__ int cnt[C_], start[C_], fill[C_];
    int tid = threadIdx.x;
    if (tid < C_) cnt[tid] = 0;
    if (tid < NSLOT) { tcam[tid] = -1; toff[tid] = 0; tcnt[tid] = 0; }
    __syncthreads();
    for (int b = tid; b < B_; b += 256) atomicAdd(&cnt[cam[b]], 1);
    __syncthreads();
    if (tid == 0) {
        int run = 0;
        for (int c = 0; c < C_; ++c) { start[c] = run; fill[c] = run; run += cnt[c]; }
    }
    __syncthreads();
    for (int b = tid; b < B_; b += 256) {
        int pos = atomicAdd(&fill[cam[b]], 1);
        order[pos] = b;
    }
    __syncthreads();
    if (tid == 0) {
        int gcnt[8] = {0,0,0,0,0,0,0,0};
        for (int c = 0; c < C_; ++c) gcnt[c & 7] += (cnt[c] + TS - 1) / TS;
        int maxg = 0;
        for (int g = 0; g < 8; ++g) maxg = max(maxg, gcnt[g]);
        if (maxg <= MAXG) {
            // camera c tiles land on slots ≡ (c&7) mod 8 -> stable XCD -> weights L2-resident
            for (int g = 0; g < 8; ++g) {
                int k = 0;
                for (int c = g; c < C_; c += 8)
                    for (int r = 0; r < cnt[c]; r += TS) {
                        int slot = g + 8 * k;
                        tcam[slot] = c; toff[slot] = start[c] + r;
                        tcnt[slot] = min(TS, cnt[c] - r); ++k;
                    }
            }
        } else {
            int ti = 0;
            for (int c = 0; c < C_; ++c)
                for (int r = 0; r < cnt[c]; r += TS) {
                    tcam[ti] = c; toff[ti] = start[c] + r;
                    tcnt[ti] = min(TS, cnt[c] - r); ++ti;
                }
        }
    }
}

// ---------------- fp32 -> bf16 row-major (Wih for gi kernel) ----------------
__global__ __launch_bounds__(256) void cvt_kernel(const float* __restrict__ src,
    unsigned short* __restrict__ dst, int n4)
{
    int i = blockIdx.x * 256 + threadIdx.x;
    if (i < n4) {
        float4 v = ((const float4*)src)[i];
        unsigned p0 = (unsigned)f2bf(v.x) | ((unsigned)f2bf(v.y) << 16);
        unsigned p1 = (unsigned)f2bf(v.z) | ((unsigned)f2bf(v.w) << 16);
        ((uint2*)dst)[i] = make_uint2(p0, p1);
    }
}

// ---------------- pack Whh|Wc -> bf16 in exact B-fragment order ----------------
// Wpack[c][u][kk][lane][8]: unit u covers cols u*16..+15 (u<48: Whh, else Wc);
// lane (q=lane>>4, l16=lane&15): col=u*16+l16, k=kk*32+q*8 .. +8
__global__ __launch_bounds__(64) void pack_kernel(
    const float* __restrict__ Whh, const float* __restrict__ Wc,
    unsigned short* __restrict__ Wpack)
{
    int cu = blockIdx.x;               // c*NU + u
    int c = cu / NU, u = cu - c * NU;
    int lane = threadIdx.x, q = lane >> 4, l16 = lane & 15;
    const float* src = (u < 48)
        ? &Whh[((size_t)c * G3H_ + u * 16 + l16) * H_]
        : &Wc[((size_t)c * O_ + (u - 48) * 16 + l16) * H_];
    unsigned short* dst = Wpack + ((size_t)cu * 8) * 512 + lane * 8;
#pragma unroll
    for (int kk = 0; kk < 8; ++kk) {
        float4 v0 = *(const float4*)&src[kk * 32 + q * 8];
        float4 v1 = *(const float4*)&src[kk * 32 + q * 8 + 4];
        unsigned short* d = dst + kk * 512;
        d[0] = f2bf(v0.x); d[1] = f2bf(v0.y); d[2] = f2bf(v0.z); d[3] = f2bf(v0.w);
        d[4] = f2bf(v1.x); d[5] = f2bf(v1.y); d[6] = f2bf(v1.z); d[7] = f2bf(v1.w);
    }
}

// ---------------- gi = x*Wih^T + b_ih + b_hh(r,z) via MFMA (R3, proven) ----------------
__global__ __launch_bounds__(384) void gi_mfma(
    const float* __restrict__ x, const unsigned short* __restrict__ Wih_b,
    const float* __restrict__ bih, const float* __restrict__ bhh,
    const int* __restrict__ order, const int* __restrict__ tcam,
    const int* __restrict__ toff, const int* __restrict__ tcnt,
    float* __restrict__ gi)
{
    int c = tcam[blockIdx.x]; if (c < 0) return;
    int cnt = tcnt[blockIdx.x], off = toff[blockIdx.x];
    int tid = threadIdx.x;
    __shared__ unsigned short hbfs[TS * 264];
    __shared__ int ord16[TS];
    if (tid < TS) ord16[tid] = (tid < cnt) ? order[off + tid] : 0;
    for (int idx = tid; idx < TS * 64; idx += 384) {
        int m = idx >> 6, c4 = idx & 63;
        float4 v = make_float4(0.f, 0.f, 0.f, 0.f);
        if (m < cnt) v = *(const float4*)&x[(size_t)order[off + m] * H_ + (c4 << 2)];
        unsigned p0 = (unsigned)f2bf(v.x) | ((unsigned)f2bf(v.y) << 16);
        unsigned p1 = (unsigned)f2bf(v.z) | ((unsigned)f2bf(v.w) << 16);
        *(uint2*)&hbfs[m * 264 + (c4 << 2)] = make_uint2(p0, p1);
    }
    __syncthreads();
    int w = tid >> 6, lane = tid & 63, q = lane >> 4, l16 = lane & 15;
    f32x4 acc[2][4];
#pragma unroll
    for (int i = 0; i < 2; ++i)
#pragma unroll
        for (int nt = 0; nt < 4; ++nt) acc[i][nt] = (f32x4){0.f, 0.f, 0.f, 0.f};
    const unsigned short* bp[2];
#pragma unroll
    for (int i = 0; i < 2; ++i)
        bp[i] = Wih_b + ((size_t)c * G3H_ + (2 * w + i) * 64 + l16) * H_;
    const unsigned short* ap = &hbfs[l16 * 264 + q * 8];
#pragma unroll 2
    for (int kk = 0; kk < 8; ++kk) {
        bf16x8 a = *(const bf16x8*)(ap + kk * 32);
#pragma unroll
        for (int i = 0; i < 2; ++i)
#pragma unroll
            for (int nt = 0; nt < 4; ++nt) {
                bf16x8 b = *(const bf16x8*)(bp[i] + (size_t)nt * 16 * H_ + kk * 32 + q * 8);
                acc[i][nt] = __builtin_amdgcn_mfma_f32_16x16x32_bf16(a, b, acc[i][nt], 0, 0, 0);
            }
    }
#pragma unroll
    for (int i = 0; i < 2; ++i) {
        int u = 2 * w + i;
#pragma unroll
        for (int nt = 0; nt < 4; ++nt) {
            int col = u * 64 + nt * 16 + l16;
            float bias = bih[c * G3H_ + col] + (col < 2 * H_ ? bhh[c * G3H_ + col] : 0.f);
#pragma unroll
            for (int r = 0; r < 4; ++r) {
                int m = q * 4 + r;
                if (m < cnt) gi[(size_t)ord16[m] * G3H_ + col] = acc[i][nt][r] + bias;
            }
        }
    }
}

// ---------------- persistent per-tile: block owns 16 samples for all 60 steps ----------------
// No cross-block communication: h in VGPRs, h_bf16 + gh preacts in LDS, weights streamed
// from (XCD-pinned) L2 in packed fragment order.
__global__ __launch_bounds__(512, 2) void persist_kernel(
    const unsigned short* __restrict__ Wpack, const float* __restrict__ bc,
    const float* __restrict__ bhh, const float* __restrict__ gi,
    const int* __restrict__ order, const int* __restrict__ tcam,
    const int* __restrict__ toff, const int* __restrict__ tcnt,
    unsigned short* __restrict__ outT, int direct, float* __restrict__ outp)
{
    int c = tcam[blockIdx.x]; if (c < 0) return;
    int n = tcnt[blockIdx.x], off = toff[blockIdx.x];
    int tid = threadIdx.x, w = tid >> 6, lane = tid & 63, q = lane >> 4, l16 = lane & 15;

    __shared__ float P[16][772];             // gh preacts, row pad +4 (2-way banks = free)
    __shared__ unsigned short hbf[16][264];  // bf16 h, row pad +8

    for (int i = tid; i < 16 * 772; i += 512) ((float*)P)[i] = 0.f;
    for (int i = tid; i < 16 * 264; i += 512) ((unsigned short*)hbf)[i] = 0;

    // update role: thread handles col=tid&255, samples (tid>>8)*8 .. +7
    int ucol = tid & 255, mh = tid >> 8;
    float ugr[8], ugz[8], ugn[8], hreg[8];
#pragma unroll
    for (int i = 0; i < 8; ++i) {
        int m = mh * 8 + i;
        int b = (m < n) ? order[off + m] : 0;
        const float* gb = gi + (size_t)b * G3H_;
        ugr[i] = gb[ucol]; ugz[i] = gb[H_ + ucol]; ugn[i] = gb[2 * H_ + ucol];
        hreg[i] = 0.f;
    }
    float bhn = bhh[c * G3H_ + 2 * H_ + ucol];

    // MFMA role: wave w owns units w*UW .. +UW-1 (16 cols each)
    int ord4[4];
#pragma unroll
    for (int r = 0; r < 4; ++r) {
        int m = q * 4 + r;
        ord4[r] = (m < n) ? order[off + m] : -1;
    }
    float bcr[UW];
#pragma unroll
    for (int ui = 0; ui < UW; ++ui) {
        int u = w * UW + ui;
        bcr[ui] = (u >= 48) ? bc[c * O_ + (u - 48) * 16 + l16] : 0.f;
    }
    const unsigned short* wbase = Wpack + (size_t)c * NU * 8 * 512 + lane * 8;
    __syncthreads();

    for (int s = 0; s <= T_; ++s) {
        if (s > 0) {
            bf16x8 a[8];
#pragma unroll
            for (int kk = 0; kk < 8; ++kk)
                a[kk] = *(const bf16x8*)&hbf[l16][kk * 32 + q * 8];
            f32x4 acc[UW];
            bf16x8 bnx[8];
            {
                const unsigned short* p = wbase + (size_t)(w * UW) * 8 * 512;
#pragma unroll
                for (int kk = 0; kk < 8; ++kk) bnx[kk] = *(const bf16x8*)(p + kk * 512);
            }
#pragma unroll
            for (int ui = 0; ui < UW; ++ui) {
                bf16x8 bcur[8];
#pragma unroll
                for (int kk = 0; kk < 8; ++kk) bcur[kk] = bnx[kk];
                if (ui < UW - 1) {
                    const unsigned short* p = wbase + (size_t)(w * UW + ui + 1) * 8 * 512;
#pragma unroll
                    for (int kk = 0; kk < 8; ++kk) bnx[kk] = *(const bf16x8*)(p + kk * 512);
                }
                f32x4 acu = {0.f, 0.f, 0.f, 0.f};
#pragma unroll
                for (int kk = 0; kk < 8; ++kk)
                    acu = __builtin_amdgcn_mfma_f32_16x16x32_bf16(a[kk], bcur[kk], acu, 0, 0, 0);
                acc[ui] = acu;
            }
#pragma unroll
            for (int ui = 0; ui < UW; ++ui) {
                int u = w * UW + ui;
                if (u < 48) {
                    if (s < T_) {
                        int col = u * 16 + l16;
#pragma unroll
                        for (int r = 0; r < 4; ++r) P[q * 4 + r][col] = acc[ui][r];
                    }
                } else {
                    int o = (u - 48) * 16 + l16, t = s - 1;
#pragma unroll
                    for (int r = 0; r < 4; ++r) {
                        if (ord4[r] >= 0) {
                            float val = sigf(acc[ui][r] + bcr[ui]);
                            if (direct) outp[((size_t)ord4[r] * O_ + o) * T_ + t] = val;
                            else outT[((size_t)t * B_ + ord4[r]) * O_ + o] =
                                     __half_as_ushort(__float2half_rn(val));
                        }
                    }
                }
            }
        }
        if (s == T_) break;
        __syncthreads();
#pragma unroll
        for (int i = 0; i < 8; ++i) {
            int m = mh * 8 + i;
            float rr = sigf(ugr[i] + P[m][ucol]);
            float zz = sigf(ugz[i] + P[m][H_ + ucol]);
            float pre = ugn[i] + rr * (P[m][2 * H_ + ucol] + bhn);
            float nn = 2.f * sigf(2.f * pre) - 1.f;          // tanh
            float hnew = (1.f - zz) * nn + zz * hreg[i];
            hreg[i] = hnew;
            hbf[m][ucol] = f2bf(hnew);
        }
        __syncthreads();
    }
}

// ---------------- transpose [T][B][O] fp16 -> [B][O][T] fp32 ----------------
__global__ __launch_bounds__(256) void transpose_kernel(
    const unsigned short* __restrict__ outT, float* __restrict__ outp)
{
    int b = blockIdx.x, o0 = blockIdx.y * 64;
    __shared__ float ts[T_][65];
    int tid = threadIdx.x;
    for (int idx = tid; idx < T_ * 64; idx += 256) {
        int t = idx >> 6, o = idx & 63;
        ts[t][o] = __half2float(__ushort_as_half(outT[((size_t)t * B_ + b) * O_ + o0 + o]));
    }
    __syncthreads();
    for (int idx = tid; idx < 64 * T_; idx += 256) {
        int o = idx / T_, t = idx - o * T_;
        outp[((size_t)b * O_ + o0 + o) * T_ + t] = ts[t][o];
    }
}

extern "C" void kernel_launch(void* const* d_in, const int* in_sizes, int n_in,
                              void* d_out, int out_size, void* d_ws, size_t ws_size,
                              hipStream_t stream)
{
    const float* x   = (const float*)d_in[0];
    const int*   cam = (const int*)d_in[1];
    const float* Wih = (const float*)d_in[2];
    const float* Whh = (const float*)d_in[3];
    const float* bih = (const float*)d_in[4];
    const float* bhh = (const float*)d_in[5];
    const float* Wc  = (const float*)d_in[6];
    const float* bc  = (const float*)d_in[7];
    float* outp = (float*)d_out;

    char* w = (char*)d_ws;
    unsigned short* Wih_b = (unsigned short*)w; w += (size_t)C_ * G3H_ * H_ * 2;
    unsigned short* Wpack = (unsigned short*)w; w += (size_t)C_ * NU * 8 * 512 * 2;
    int* order = (int*)w; w += B_ * 4;
    int* tcam  = (int*)w; w += NSLOT * 4;
    int* toff  = (int*)w; w += NSLOT * 4;
    int* tcnt  = (int*)w; w += NSLOT * 4;
    float* gi  = (float*)w; w += (size_t)B_ * G3H_ * 4;
    unsigned short* outT = (unsigned short*)w;
    size_t need = (size_t)(w - (char*)d_ws) + (size_t)T_ * B_ * O_ * 2;
    int direct = (ws_size < need) ? 1 : 0;

    sort_kernel<<<1, 256, 0, stream>>>(cam, order, tcam, toff, tcnt);
    cvt_kernel<<<(C_ * G3H_ * H_ / 4 + 255) / 256, 256, 0, stream>>>(Wih, Wih_b, C_ * G3H_ * H_ / 4);
    pack_kernel<<<C_ * NU, 64, 0, stream>>>(Whh, Wc, Wpack);
    gi_mfma<<<NSLOT, 384, 0, stream>>>(x, Wih_b, bih, bhh, order, tcam, toff, tcnt, gi);
    persist_kernel<<<NSLOT, 512, 0, stream>>>(Wpack, bc, bhh, gi, order, tcam, toff, tcnt,
                                              outT, direct, outp);
    if (!direct)
        transpose_kernel<<<dim3(B_, O_ / 64), 256, 0, stream>>>(outT, outp);
}

// Round 6
// 502.745 us; speedup vs baseline: 10.4005x; 2.0822x over previous
//
#include <hip/hip_runtime.h>
#include <hip/hip_fp16.h>

#define C_    15
#define H_    256
#define O_    512
#define T_    60
#define B_    1024
#define G3H_  768
#define TS    16
#define MAXG  12
#define NSLOT 96
#define NU    80          // packed 16-col units per camera: 48 gh + 32 out
#define TCH   10          // t-steps per out-kernel block

typedef __attribute__((ext_vector_type(8))) short bf16x8;
typedef __attribute__((ext_vector_type(4))) float f32x4;

__device__ __forceinline__ unsigned short f2bf(float f) {
    union { float f; unsigned u; } v; v.f = f;
    return (unsigned short)((v.u + 0x7FFFu + ((v.u >> 16) & 1u)) >> 16);   // RTNE
}
__device__ __forceinline__ float sigf(float x) { return 1.f / (1.f + __expf(-x)); }

// ---------------- sort: camera grouping, XCD-pinned 16-row tile table ----------------
__global__ __launch_bounds__(256) void sort_kernel(const int* __restrict__ cam,
    int* __restrict__ order, int* __restrict__ tcam, int* __restrict__ toff,
    int* __restrict__ tcnt)
{
    __shared__ int cnt[C_], start[C_], fill[C_];
    int tid = threadIdx.x;
    if (tid < C_) cnt[tid] = 0;
    if (tid < NSLOT) { tcam[tid] = -1; toff[tid] = 0; tcnt[tid] = 0; }
    __syncthreads();
    for (int b = tid; b < B_; b += 256) atomicAdd(&cnt[cam[b]], 1);
    __syncthreads();
    if (tid == 0) {
        int run = 0;
        for (int c = 0; c < C_; ++c) { start[c] = run; fill[c] = run; run += cnt[c]; }
    }
    __syncthreads();
    for (int b = tid; b < B_; b += 256) {
        int pos = atomicAdd(&fill[cam[b]], 1);
        order[pos] = b;
    }
    __syncthreads();
    if (tid == 0) {
        int gcnt[8] = {0,0,0,0,0,0,0,0};
        for (int c = 0; c < C_; ++c) gcnt[c & 7] += (cnt[c] + TS - 1) / TS;
        int maxg = 0;
        for (int g = 0; g < 8; ++g) maxg = max(maxg, gcnt[g]);
        if (maxg <= MAXG) {
            // camera c tiles land on slots ≡ (c&7) mod 8 -> stable XCD -> weights L2-resident
            for (int g = 0; g < 8; ++g) {
                int k = 0;
                for (int c = g; c < C_; c += 8)
                    for (int r = 0; r < cnt[c]; r += TS) {
                        int slot = g + 8 * k;
                        tcam[slot] = c; toff[slot] = start[c] + r;
                        tcnt[slot] = min(TS, cnt[c] - r); ++k;
                    }
            }
        } else {
            int ti = 0;
            for (int c = 0; c < C_; ++c)
                for (int r = 0; r < cnt[c]; r += TS) {
                    tcam[ti] = c; toff[ti] = start[c] + r;
                    tcnt[ti] = min(TS, cnt[c] - r); ++ti;
                }
        }
    }
}

// ---------------- fp32 -> bf16 row-major (Wih for gi kernel) ----------------
__global__ __launch_bounds__(256) void cvt_kernel(const float* __restrict__ src,
    unsigned short* __restrict__ dst, int n4)
{
    int i = blockIdx.x * 256 + threadIdx.x;
    if (i < n4) {
        float4 v = ((const float4*)src)[i];
        unsigned p0 = (unsigned)f2bf(v.x) | ((unsigned)f2bf(v.y) << 16);
        unsigned p1 = (unsigned)f2bf(v.z) | ((unsigned)f2bf(v.w) << 16);
        ((uint2*)dst)[i] = make_uint2(p0, p1);
    }
}

// ---------------- pack Whh|Wc -> bf16 in exact B-fragment order ----------------
__global__ __launch_bounds__(64) void pack_kernel(
    const float* __restrict__ Whh, const float* __restrict__ Wc,
    unsigned short* __restrict__ Wpack)
{
    int cu = blockIdx.x;               // c*NU + u
    int c = cu / NU, u = cu - c * NU;
    int lane = threadIdx.x, q = lane >> 4, l16 = lane & 15;
    const float* src = (u < 48)
        ? &Whh[((size_t)c * G3H_ + u * 16 + l16) * H_]
        : &Wc[((size_t)c * O_ + (u - 48) * 16 + l16) * H_];
    unsigned short* dst = Wpack + ((size_t)cu * 8) * 512 + lane * 8;
#pragma unroll
    for (int kk = 0; kk < 8; ++kk) {
        float4 v0 = *(const float4*)&src[kk * 32 + q * 8];
        float4 v1 = *(const float4*)&src[kk * 32 + q * 8 + 4];
        unsigned short* d = dst + kk * 512;
        d[0] = f2bf(v0.x); d[1] = f2bf(v0.y); d[2] = f2bf(v0.z); d[3] = f2bf(v0.w);
        d[4] = f2bf(v1.x); d[5] = f2bf(v1.y); d[6] = f2bf(v1.z); d[7] = f2bf(v1.w);
    }
}

// ---------------- gi = x*Wih^T + b_ih + b_hh(r,z) via MFMA (proven) ----------------
__global__ __launch_bounds__(384) void gi_mfma(
    const float* __restrict__ x, const unsigned short* __restrict__ Wih_b,
    const float* __restrict__ bih, const float* __restrict__ bhh,
    const int* __restrict__ order, const int* __restrict__ tcam,
    const int* __restrict__ toff, const int* __restrict__ tcnt,
    float* __restrict__ gi)
{
    int c = tcam[blockIdx.x]; if (c < 0) return;
    int cnt = tcnt[blockIdx.x], off = toff[blockIdx.x];
    int tid = threadIdx.x;
    __shared__ unsigned short hbfs[TS * 264];
    __shared__ int ord16[TS];
    if (tid < TS) ord16[tid] = (tid < cnt) ? order[off + tid] : 0;
    for (int idx = tid; idx < TS * 64; idx += 384) {
        int m = idx >> 6, c4 = idx & 63;
        float4 v = make_float4(0.f, 0.f, 0.f, 0.f);
        if (m < cnt) v = *(const float4*)&x[(size_t)order[off + m] * H_ + (c4 << 2)];
        unsigned p0 = (unsigned)f2bf(v.x) | ((unsigned)f2bf(v.y) << 16);
        unsigned p1 = (unsigned)f2bf(v.z) | ((unsigned)f2bf(v.w) << 16);
        *(uint2*)&hbfs[m * 264 + (c4 << 2)] = make_uint2(p0, p1);
    }
    __syncthreads();
    int w = tid >> 6, lane = tid & 63, q = lane >> 4, l16 = lane & 15;
    f32x4 acc[2][4];
#pragma unroll
    for (int i = 0; i < 2; ++i)
#pragma unroll
        for (int nt = 0; nt < 4; ++nt) acc[i][nt] = (f32x4){0.f, 0.f, 0.f, 0.f};
    const unsigned short* bp[2];
#pragma unroll
    for (int i = 0; i < 2; ++i)
        bp[i] = Wih_b + ((size_t)c * G3H_ + (2 * w + i) * 64 + l16) * H_;
    const unsigned short* ap = &hbfs[l16 * 264 + q * 8];
#pragma unroll 2
    for (int kk = 0; kk < 8; ++kk) {
        bf16x8 a = *(const bf16x8*)(ap + kk * 32);
#pragma unroll
        for (int i = 0; i < 2; ++i)
#pragma unroll
            for (int nt = 0; nt < 4; ++nt) {
                bf16x8 b = *(const bf16x8*)(bp[i] + (size_t)nt * 16 * H_ + kk * 32 + q * 8);
                acc[i][nt] = __builtin_amdgcn_mfma_f32_16x16x32_bf16(a, b, acc[i][nt], 0, 0, 0);
            }
    }
#pragma unroll
    for (int i = 0; i < 2; ++i) {
        int u = 2 * w + i;
#pragma unroll
        for (int nt = 0; nt < 4; ++nt) {
            int col = u * 64 + nt * 16 + l16;
            float bias = bih[c * G3H_ + col] + (col < 2 * H_ ? bhh[c * G3H_ + col] : 0.f);
#pragma unroll
            for (int r = 0; r < 4; ++r) {
                int m = q * 4 + r;
                if (m < cnt) gi[(size_t)ord16[m] * G3H_ + col] = acc[i][nt][r] + bias;
            }
        }
    }
}

// ---------------- persistent recurrence: gh weights live in VGPRs for all 60 steps ----------------
// Per block: 16 samples; 8 waves x 6 units x 8 kk x 4 VGPR = 192 weight VGPRs/thread.
// Zero global traffic in the loop except the 8KB/step h-trajectory write.
__global__ __launch_bounds__(512, 2) void persist_kernel(
    const unsigned short* __restrict__ Wpack, const float* __restrict__ bhh,
    const float* __restrict__ gi, const int* __restrict__ order,
    const int* __restrict__ tcam, const int* __restrict__ toff,
    const int* __restrict__ tcnt, unsigned short* __restrict__ htraj)
{
    int slot = blockIdx.x;
    int c = tcam[slot]; if (c < 0) return;
    int n = tcnt[slot], off = toff[slot];
    int tid = threadIdx.x, w = tid >> 6, lane = tid & 63, q = lane >> 4, l16 = lane & 15;

    __shared__ float gis[16][772];           // staged gi (48.3 KB)
    __shared__ float P[16][772];             // gh preacts (48.3 KB)
    __shared__ float hfp[16][260];           // fp32 h state (16.6 KB)
    __shared__ unsigned short hbf[16][264];  // bf16 h (8.4 KB)

    for (int i = tid; i < 16 * 772; i += 512) ((float*)P)[i] = 0.f;
    for (int i = tid; i < 16 * 260; i += 512) ((float*)hfp)[i] = 0.f;
    for (int i = tid; i < 16 * 264; i += 512) ((unsigned short*)hbf)[i] = 0;
    for (int idx = tid; idx < 16 * 192; idx += 512) {       // 192 float4 per gi row
        int m = idx / 192, c4 = idx - m * 192;
        float4 v = make_float4(0.f, 0.f, 0.f, 0.f);
        if (m < n) v = *(const float4*)&gi[(size_t)order[off + m] * G3H_ + (c4 << 2)];
        *(float4*)&gis[m][c4 << 2] = v;
    }

    // weights -> VGPRs once
    bf16x8 wf[6][8];
    const unsigned short* wb = Wpack + ((size_t)c * NU + w * 6) * 8 * 512 + lane * 8;
#pragma unroll
    for (int ui = 0; ui < 6; ++ui)
#pragma unroll
        for (int kk = 0; kk < 8; ++kk)
            wf[ui][kk] = *(const bf16x8*)(wb + ((size_t)ui * 8 + kk) * 512);

    int ucol = tid & 255, mh = (tid >> 8) * 8;
    float bhn = bhh[c * G3H_ + 2 * H_ + ucol];
    __syncthreads();

    for (int s = 0; s < T_; ++s) {
        if (s > 0) {
            f32x4 acc[6];
#pragma unroll
            for (int ui = 0; ui < 6; ++ui) acc[ui] = (f32x4){0.f, 0.f, 0.f, 0.f};
#pragma unroll
            for (int kk = 0; kk < 8; ++kk) {
                bf16x8 a = *(const bf16x8*)&hbf[l16][kk * 32 + q * 8];
#pragma unroll
                for (int ui = 0; ui < 6; ++ui)
                    acc[ui] = __builtin_amdgcn_mfma_f32_16x16x32_bf16(a, wf[ui][kk], acc[ui], 0, 0, 0);
            }
#pragma unroll
            for (int ui = 0; ui < 6; ++ui) {
                int col = (w * 6 + ui) * 16 + l16;
#pragma unroll
                for (int r = 0; r < 4; ++r) P[q * 4 + r][col] = acc[ui][r];
            }
            __syncthreads();
        }
        // gate update (fp32, LDS-local) + h-trajectory write
        unsigned short* hrow = htraj + (((size_t)s * NSLOT + slot) * 16) * 256;
#pragma unroll
        for (int i = 0; i < 8; ++i) {
            int m = mh + i;
            float rr = sigf(gis[m][ucol] + P[m][ucol]);
            float zz = sigf(gis[m][256 + ucol] + P[m][256 + ucol]);
            float pre = gis[m][512 + ucol] + rr * (P[m][512 + ucol] + bhn);
            float nn = 2.f * sigf(2.f * pre) - 1.f;          // tanh
            float hnew = (1.f - zz) * nn + zz * hfp[m][ucol];
            hfp[m][ucol] = hnew;
            unsigned short hb = f2bf(hnew);
            hbf[m][ucol] = hb;
            hrow[m * 256 + ucol] = hb;
        }
        __syncthreads();
    }
}

// ---------------- out GEMM over trajectory: out[t] = sigmoid(h_{t+1} Wc^T + bc) ----------------
// grid (NSLOT, T/TCH): block = 16 samples x TCH timesteps x all 512 O-cols; B-frags in VGPRs.
__global__ __launch_bounds__(512, 2) void out_kernel(
    const unsigned short* __restrict__ Wpack, const float* __restrict__ bc,
    const unsigned short* __restrict__ htraj, const int* __restrict__ order,
    const int* __restrict__ tcam, const int* __restrict__ toff,
    const int* __restrict__ tcnt, unsigned short* __restrict__ outT,
    int direct, float* __restrict__ outp)
{
    int slot = blockIdx.x;
    int c = tcam[slot]; if (c < 0) return;
    int n = tcnt[slot], off = toff[slot];
    int tid = threadIdx.x, w = tid >> 6, lane = tid & 63, q = lane >> 4, l16 = lane & 15;
    __shared__ unsigned short hb[16][264];
    __shared__ int ord16[16];
    if (tid < 16) ord16[tid] = (tid < n) ? order[off + tid] : -1;

    bf16x8 wf[4][8];
    const unsigned short* wb = Wpack + ((size_t)c * NU + 48 + w * 4) * 8 * 512 + lane * 8;
#pragma unroll
    for (int ui = 0; ui < 4; ++ui)
#pragma unroll
        for (int kk = 0; kk < 8; ++kk)
            wf[ui][kk] = *(const bf16x8*)(wb + ((size_t)ui * 8 + kk) * 512);
    float bcr[4];
#pragma unroll
    for (int ui = 0; ui < 4; ++ui)
        bcr[ui] = bc[c * O_ + (w * 4 + ui) * 16 + l16];
    __syncthreads();

    for (int ti = 0; ti < TCH; ++ti) {
        int t = blockIdx.y * TCH + ti;
        {   // stage h tile: 512 threads x 16B = 8KB
            int m = tid >> 5, c8 = (tid & 31) * 8;
            uint4 v = *(const uint4*)&htraj[(((size_t)t * NSLOT + slot) * 16 + m) * 256 + c8];
            *(uint4*)&hb[m][c8] = v;
        }
        __syncthreads();
        f32x4 acc[4];
#pragma unroll
        for (int ui = 0; ui < 4; ++ui) acc[ui] = (f32x4){0.f, 0.f, 0.f, 0.f};
#pragma unroll
        for (int kk = 0; kk < 8; ++kk) {
            bf16x8 a = *(const bf16x8*)&hb[l16][kk * 32 + q * 8];
#pragma unroll
            for (int ui = 0; ui < 4; ++ui)
                acc[ui] = __builtin_amdgcn_mfma_f32_16x16x32_bf16(a, wf[ui][kk], acc[ui], 0, 0, 0);
        }
#pragma unroll
        for (int ui = 0; ui < 4; ++ui) {
            int o = (w * 4 + ui) * 16 + l16;
#pragma unroll
            for (int r = 0; r < 4; ++r) {
                int b = ord16[q * 4 + r];
                if (b >= 0) {
                    float val = sigf(acc[ui][r] + bcr[ui]);
                    if (direct) outp[((size_t)b * O_ + o) * T_ + t] = val;
                    else outT[((size_t)t * B_ + b) * O_ + o] =
                             __half_as_ushort(__float2half_rn(val));
                }
            }
        }
        __syncthreads();
    }
}

// ---------------- transpose [T][B][O] fp16 -> [B][O][T] fp32 ----------------
__global__ __launch_bounds__(256) void transpose_kernel(
    const unsigned short* __restrict__ outT, float* __restrict__ outp)
{
    int b = blockIdx.x, o0 = blockIdx.y * 64;
    __shared__ float ts[T_][65];
    int tid = threadIdx.x;
    for (int idx = tid; idx < T_ * 64; idx += 256) {
        int t = idx >> 6, o = idx & 63;
        ts[t][o] = __half2float(__ushort_as_half(outT[((size_t)t * B_ + b) * O_ + o0 + o]));
    }
    __syncthreads();
    for (int idx = tid; idx < 64 * T_; idx += 256) {
        int o = idx / T_, t = idx - o * T_;
        outp[((size_t)b * O_ + o0 + o) * T_ + t] = ts[t][o];
    }
}

extern "C" void kernel_launch(void* const* d_in, const int* in_sizes, int n_in,
                              void* d_out, int out_size, void* d_ws, size_t ws_size,
                              hipStream_t stream)
{
    const float* x   = (const float*)d_in[0];
    const int*   cam = (const int*)d_in[1];
    const float* Wih = (const float*)d_in[2];
    const float* Whh = (const float*)d_in[3];
    const float* bih = (const float*)d_in[4];
    const float* bhh = (const float*)d_in[5];
    const float* Wc  = (const float*)d_in[6];
    const float* bc  = (const float*)d_in[7];
    float* outp = (float*)d_out;

    char* w = (char*)d_ws;
    unsigned short* Wih_b = (unsigned short*)w; w += (size_t)C_ * G3H_ * H_ * 2;
    unsigned short* Wpack = (unsigned short*)w; w += (size_t)C_ * NU * 8 * 512 * 2;
    int* order = (int*)w; w += B_ * 4;
    int* tcam  = (int*)w; w += NSLOT * 4;
    int* toff  = (int*)w; w += NSLOT * 4;
    int* tcnt  = (int*)w; w += NSLOT * 4;
    float* gi  = (float*)w; w += (size_t)B_ * G3H_ * 4;
    unsigned short* htraj = (unsigned short*)w; w += (size_t)T_ * NSLOT * 16 * 256 * 2;
    unsigned short* outT = (unsigned short*)w;
    size_t need = (size_t)(w - (char*)d_ws) + (size_t)T_ * B_ * O_ * 2;
    int direct = (ws_size < need) ? 1 : 0;

    sort_kernel<<<1, 256, 0, stream>>>(cam, order, tcam, toff, tcnt);
    cvt_kernel<<<(C_ * G3H_ * H_ / 4 + 255) / 256, 256, 0, stream>>>(Wih, Wih_b, C_ * G3H_ * H_ / 4);
    pack_kernel<<<C_ * NU, 64, 0, stream>>>(Whh, Wc, Wpack);
    gi_mfma<<<NSLOT, 384, 0, stream>>>(x, Wih_b, bih, bhh, order, tcam, toff, tcnt, gi);
    persist_kernel<<<NSLOT, 512, 0, stream>>>(Wpack, bhh, gi, order, tcam, toff, tcnt, htraj);
    out_kernel<<<dim3(NSLOT, T_ / TCH), 512, 0, stream>>>(Wpack, bc, htraj, order, tcam,
                                                          toff, tcnt, outT, direct, outp);
    if (!direct)
        transpose_kernel<<<dim3(B_, O_ / 64), 256, 0, stream>>>(outT, outp);
}